// Round 1
// baseline (421.103 us; speedup 1.0000x reference)
//
#include <hip/hip_runtime.h>
#include <math.h>

#define NEXP 32
#define NTOK 256
#define DIMD 768
#define DHID 2048
#define DBOT 256
#define DOUT 768
#define NSLOT 512

// ---------------- gate: logits -> top2 -> weights; init y with bl; zero z ----------------
__global__ __launch_bounds__(64) void gate_kernel(
    const float* __restrict__ x, const float* __restrict__ gw,
    const float* __restrict__ bl, float* __restrict__ y,
    int* __restrict__ topk_idx, float* __restrict__ topk_w,
    float* __restrict__ z) {
  const int n = blockIdx.x;
  const int l = threadIdx.x;
  // zero z accumulator slice (512 floats per block)
  {
    float4 zv = {0.f, 0.f, 0.f, 0.f};
    float4* zp = (float4*)(z + n * 512 + l * 8);
    zp[0] = zv; zp[1] = zv;
  }
  const float* xr = x + n * DIMD;
  float xs[12];
#pragma unroll
  for (int j = 0; j < 12; j++) xs[j] = xr[l + 64 * j];
  float logit[NEXP];
#pragma unroll
  for (int e = 0; e < NEXP; e++) {
    const float* g = gw + e * DIMD;
    float p = 0.f;
#pragma unroll
    for (int j = 0; j < 12; j++) p = fmaf(xs[j], g[l + 64 * j], p);
#pragma unroll
    for (int m = 1; m < 64; m <<= 1) p += __shfl_xor(p, m);
    logit[e] = p;
  }
  int i0 = 0; float m0 = logit[0];
#pragma unroll
  for (int e = 1; e < NEXP; e++) { if (logit[e] > m0) { m0 = logit[e]; i0 = e; } }
  int i1 = -1; float m1 = -3.4e38f;
#pragma unroll
  for (int e = 0; e < NEXP; e++) { if (e != i0 && logit[e] > m1) { m1 = logit[e]; i1 = e; } }
  // softmax denominators cancel in renormalization: w0 = e^{l0}/(e^{l0}+e^{l1})
  const float e1 = expf(m1 - m0);
  const float w0 = 1.f / (1.f + e1);
  const float w1 = e1 * w0;
  if (l == 0) {
    topk_idx[2 * n] = i0; topk_idx[2 * n + 1] = i1;
    topk_w[2 * n] = w0;  topk_w[2 * n + 1] = w1;
  }
  const float* bl0 = bl + i0 * DOUT;
  const float* bl1 = bl + i1 * DOUT;
#pragma unroll
  for (int j = 0; j < 12; j++) {
    const int o = l + 64 * j;
    y[n * DOUT + o] = fmaf(w0, bl0[o], w1 * bl1[o]);
  }
}

// ---------------- build compact per-expert token lists ----------------
__global__ __launch_bounds__(256) void build_lists(
    const int* __restrict__ topk_idx, const float* __restrict__ topk_w,
    int* __restrict__ counts, int* __restrict__ offsets,
    int* __restrict__ tok_list, float* __restrict__ tok_wt) {
  __shared__ int cnt[NEXP], base[NEXP], fill[NEXP];
  const int t = threadIdx.x;
  if (t < NEXP) { cnt[t] = 0; fill[t] = 0; }
  __syncthreads();
  const int e0 = topk_idx[2 * t], e1 = topk_idx[2 * t + 1];
  atomicAdd(&cnt[e0], 1);
  atomicAdd(&cnt[e1], 1);
  __syncthreads();
  if (t == 0) { int s = 0; for (int i = 0; i < NEXP; i++) { base[i] = s; s += cnt[i]; } }
  __syncthreads();
  const int p0 = atomicAdd(&fill[e0], 1);
  tok_list[base[e0] + p0] = t; tok_wt[base[e0] + p0] = topk_w[2 * t];
  const int p1 = atomicAdd(&fill[e1], 1);
  tok_list[base[e1] + p1] = t; tok_wt[base[e1] + p1] = topk_w[2 * t + 1];
  if (t < NEXP) { counts[t] = cnt[t]; offsets[t] = base[t]; }
}

__device__ __forceinline__ float gelu_f(float v) {
  return 0.5f * v * (1.f + erff(v * 0.70710678118654752f));
}

// ---------------- generic expert FF layer ----------------
// MODE 0: L1  x(gather tok) @ W1 + b1 -> gelu -> h1
// MODE 1: L2  h1 @ W2 + b2 -> gelu -> h2
// MODE 2: L3  h2 @ W3 (K grid-split, atomicAdd) -> z  (b3 folded into L4 load)
// MODE 3: L4  (z + b3) @ Wl -> atomicAdd(w_t * val) into y[token]
// Block: 1024 thr = 16 waves = 2 colgroups(128 cols) x 8 K-slices; tile = 256 cols.
template <int MODE>
__global__ __launch_bounds__(1024) void ff_kernel(
    const float* __restrict__ Ain, const float* __restrict__ W,
    const float* __restrict__ Bias, float* __restrict__ Out,
    const int* __restrict__ offsets, const int* __restrict__ counts,
    const int* __restrict__ tok_list, const float* __restrict__ tok_wt,
    int KTOT, int NCT, int INS, int kblocks, int coltiles) {
  __shared__ float lds[32768];  // 128 KiB: staging (<=64K) + reduction (128K), reused
  const int tid  = threadIdx.x;
  const int lane = tid & 63;
  const int wave = tid >> 6;
  const int cg   = wave & 1;   // col-group
  const int ks   = wave >> 1;  // K-slice 0..7
  const int e    = blockIdx.y;
  const int ct   = blockIdx.x % coltiles;
  const int kb   = blockIdx.x / coltiles;
  const int KB   = KTOT / kblocks;
  const int cnt  = counts[e];
  const int off  = offsets[e];
  const int cb   = ct * 256;
  const float* Wblk = W + ((size_t)e * KTOT + (size_t)kb * KB) * NCT + cb;
  const int wcol = cg * 128 + lane;

  for (int tc0 = 0; tc0 < cnt; tc0 += 32) {
    const int tcn = min(32, cnt - tc0);
    float acc[2][32];
#pragma unroll
    for (int c = 0; c < 2; c++)
#pragma unroll
      for (int t = 0; t < 32; t++) acc[c][t] = 0.f;

    for (int sb = 0; sb < KB; sb += 512) {
      const int sec = min(512, KB - sb);
      __syncthreads();
      // ---- stage activation chunk [tcn x sec] into LDS (token-major) ----
      {
        const int t  = tid >> 5;
        const int per = sec >> 5;            // 8 or 16 floats per thread
        const int r0 = (tid & 31) * per;
        if (t < tcn) {
          const int slot = off + tc0 + t;
          const float* src;
          if (MODE == 0) src = Ain + (size_t)tok_list[slot] * INS + kb * KB + sb + r0;
          else           src = Ain + (size_t)slot * INS + kb * KB + sb + r0;
          float* dst = &lds[t * sec + r0];
          for (int j = 0; j < per; j += 4) {
            float4 v = *(const float4*)(src + j);
            if (MODE == 3) {  // fold b3 into the input
              const float4 bv = *(const float4*)(Bias + e * KTOT + sb + r0 + j);
              v.x += bv.x; v.y += bv.y; v.z += bv.z; v.w += bv.w;
            }
            *(float4*)(dst + j) = v;
          }
        }
      }
      __syncthreads();
      // ---- compute: each wave covers its K-slice of this section ----
      const int srows = sec >> 3;   // rows per slice (32 or 64)
      const int rs = ks * srows;
      for (int g = 0; g < srows; g += 4) {
        float w0[4], w1[4];
        const float* wp = Wblk + (size_t)(sb + rs + g) * NCT + wcol;
#pragma unroll
        for (int j = 0; j < 4; j++) {
          w0[j] = wp[(size_t)j * NCT];
          w1[j] = wp[(size_t)j * NCT + 64];
        }
#pragma unroll
        for (int t = 0; t < 32; t++) {
          const float4 xv = *(const float4*)&lds[t * sec + rs + g];
          acc[0][t] = fmaf(xv.x, w0[0], acc[0][t]);
          acc[0][t] = fmaf(xv.y, w0[1], acc[0][t]);
          acc[0][t] = fmaf(xv.z, w0[2], acc[0][t]);
          acc[0][t] = fmaf(xv.w, w0[3], acc[0][t]);
          acc[1][t] = fmaf(xv.x, w1[0], acc[1][t]);
          acc[1][t] = fmaf(xv.y, w1[1], acc[1][t]);
          acc[1][t] = fmaf(xv.z, w1[2], acc[1][t]);
          acc[1][t] = fmaf(xv.w, w1[3], acc[1][t]);
        }
      }
    }
    // ---- reduce 8 K-slices via LDS, then emit ----
#pragma unroll
    for (int c = 0; c < 2; c++) {
      __syncthreads();
#pragma unroll
      for (int t = 0; t < 32; t++) lds[t * 1024 + tid] = acc[c][t];
      __syncthreads();
      const int p  = tid & 127;          // (cg, lane) position
      const int t0 = (tid >> 7) << 2;    // 4 tokens per thread
      for (int i = 0; i < 4; i++) {
        const int t = t0 + i;
        if (t >= tcn) break;
        float s = 0.f;
#pragma unroll
        for (int k2 = 0; k2 < 8; k2++) s += lds[t * 1024 + k2 * 128 + p];
        const int col  = cb + (p >> 6) * 128 + c * 64 + (p & 63);
        const int slot = off + tc0 + t;
        if (MODE <= 1) {
          Out[(size_t)slot * NCT + col] = gelu_f(s + Bias[e * NCT + col]);
        } else if (MODE == 2) {
          atomicAdd(&Out[(size_t)slot * NCT + col], s);
        } else {
          atomicAdd(&Out[(size_t)tok_list[slot] * NCT + col], tok_wt[slot] * s);
        }
      }
    }
  }
}

extern "C" void kernel_launch(void* const* d_in, const int* in_sizes, int n_in,
                              void* d_out, int out_size, void* d_ws, size_t ws_size,
                              hipStream_t stream) {
  const float* x  = (const float*)d_in[0];
  const float* gw = (const float*)d_in[1];
  const float* W1 = (const float*)d_in[2];
  const float* b1 = (const float*)d_in[3];
  const float* W2 = (const float*)d_in[4];
  const float* b2 = (const float*)d_in[5];
  const float* W3 = (const float*)d_in[6];
  const float* b3 = (const float*)d_in[7];
  const float* Wl = (const float*)d_in[8];
  const float* bl = (const float*)d_in[9];
  float* y  = (float*)d_out;
  float* ws = (float*)d_ws;

  float* topk_w   = ws;                    // 512 f
  int*   topk_idx = (int*)(ws + 512);      // 512 i
  int*   counts   = (int*)(ws + 1024);     // 32 i
  int*   offsets  = (int*)(ws + 1056);     // 32 i
  int*   tok_list = (int*)(ws + 1088);     // 512 i
  float* tok_wt   = ws + 1600;             // 512 f
  float* h1 = ws + 4096;                   // 512*2048
  float* h2 = h1 + (size_t)NSLOT * DHID;   // 512*2048
  float* z  = h2 + (size_t)NSLOT * DHID;   // 512*256

  gate_kernel<<<NTOK, 64, 0, stream>>>(x, gw, bl, y, topk_idx, topk_w, z);
  build_lists<<<1, 256, 0, stream>>>(topk_idx, topk_w, counts, offsets, tok_list, tok_wt);
  // L1: x[tok,768] @ W1[e,768,2048] -> gelu -> h1       (8 coltiles x 32 experts)
  ff_kernel<0><<<dim3(8, 32), 1024, 0, stream>>>(x,  W1, b1, h1, offsets, counts, tok_list, tok_wt,
                                                 DIMD, DHID, DIMD, 1, 8);
  // L2: h1 @ W2[e,2048,2048] -> gelu -> h2              (8 coltiles x 32 experts)
  ff_kernel<1><<<dim3(8, 32), 1024, 0, stream>>>(h1, W2, b2, h2, offsets, counts, tok_list, tok_wt,
                                                 DHID, DHID, DHID, 1, 8);
  // L3: h2 @ W3[e,2048,256] -> z (atomic over 8 K-blocks)
  ff_kernel<2><<<dim3(8, 32), 1024, 0, stream>>>(h2, W3, nullptr, z, offsets, counts, tok_list, tok_wt,
                                                 DHID, DBOT, DHID, 8, 1);
  // L4: (z+b3) @ Wl[e,256,768] -> y (scatter, weighted) (3 coltiles x 32 experts)
  ff_kernel<3><<<dim3(3, 32), 1024, 0, stream>>>(z,  Wl, b3, y, offsets, counts, tok_list, tok_wt,
                                                 DBOT, DOUT, DBOT, 1, 3);
}